// Round 11
// baseline (220.655 us; speedup 1.0000x reference)
//
#include <hip/hip_runtime.h>
#include <hip/hip_bf16.h>

typedef __hip_bfloat16 bf16;
typedef __attribute__((ext_vector_type(8))) short bf16x8;
typedef __attribute__((ext_vector_type(4))) short bf16x4;
typedef __attribute__((ext_vector_type(4))) float f32x4;

// ---------------------------------------------------------------------------
// 3-layer GAT forward. Dtype-adaptive (observed world: floats=bf16, edges=i32).
// flags[0]=1 if NaN/Inf ushort pattern in x-prefix (=> x is f32)
// flags[1]=1 if any odd 32-bit word of edge prefix nonzero (=> edges i32)
// flags[2]=1 if any even-index ushort of x-prefix nonzero
// isf32 = flags[0] || !flags[2]
// ---------------------------------------------------------------------------

static __device__ __forceinline__ float bf2f(bf16 v) { return __bfloat162float(v); }
static __device__ __forceinline__ float bf2fs(short v) {
    unsigned int u = ((unsigned int)(unsigned short)v) << 16;
    return __builtin_bit_cast(float, u);
}
static __device__ __forceinline__ short f2bfs(float f) {
    bf16 b = __float2bfloat16(f);
    return __builtin_bit_cast(short, b);
}
static __device__ __forceinline__ float loadf(const void* p, size_t i, int isf32) {
    return isf32 ? ((const float*)p)[i] : bf2f(((const bf16*)p)[i]);
}
static __device__ __forceinline__ int get_isf32(const int* flags) {
    return (flags[0] | (flags[2] == 0)) ? 1 : 0;
}

// block 0: single-block detection (no atomics, direct flag store);
// blocks 1..: zero cnt[N].
__global__ void k_init(const unsigned short* __restrict__ xu, const int* __restrict__ ew,
                       int* __restrict__ flags, int* __restrict__ cnt,
                       int N, int nx, int ne2) {
    if (blockIdx.x == 0) {
        __shared__ int lf[3];
        if (threadIdx.x < 3) lf[threadIdx.x] = 0;
        __syncthreads();
        int f0 = 0, f1 = 0, f2 = 0;
        for (int i = threadIdx.x; i < nx; i += 256) {
            unsigned short v = xu[i];
            if ((v & 0x7F80u) == 0x7F80u) f0 = 1;
            if (((i & 1) == 0) && v != 0) f2 = 1;
        }
        for (int i = threadIdx.x; i < ne2; i += 256) {
            if ((i & 1) && ew[i] != 0) f1 = 1;
        }
        if (f0) lf[0] = 1;
        if (f1) lf[1] = 1;
        if (f2) lf[2] = 1;
        __syncthreads();
        if (threadIdx.x == 0) {
            flags[0] = lf[0]; flags[1] = lf[1]; flags[2] = lf[2]; flags[3] = 0;
        }
    } else {
        for (int i = (blockIdx.x - 1) * 256 + threadIdx.x; i < N;
             i += (gridDim.x - 1) * 256) cnt[i] = 0;
    }
}

// 8-elem vectorized adaptive cast
static __device__ __forceinline__ void cast8(const void* src, bf16* dst, int i8, int isf32) {
    if (isf32) {
        f32x4 a = ((const f32x4*)src)[2 * i8];
        f32x4 b = ((const f32x4*)src)[2 * i8 + 1];
        bf16x8 o;
        o[0] = f2bfs(a[0]); o[1] = f2bfs(a[1]); o[2] = f2bfs(a[2]); o[3] = f2bfs(a[3]);
        o[4] = f2bfs(b[0]); o[5] = f2bfs(b[1]); o[6] = f2bfs(b[2]); o[7] = f2bfs(b[3]);
        ((bf16x8*)dst)[i8] = o;
    } else {
        ((bf16x8*)dst)[i8] = ((const bf16x8*)src)[i8];
    }
}

// blocks [0, cb): all input casts (counts in 8-elem units).
// blocks [cb, ...): edge normalize + degree count.
__global__ void k_cast_norm(const void* s0, bf16* d0, int c0,
                            const void* s1, bf16* d1, int c1,
                            const void* s2, bf16* d2, int c2,
                            const void* s3, bf16* d3, int c3,
                            const void* s4, bf16* d4, int c4,
                            const void* s5, bf16* d5, int c5,
                            const int* __restrict__ w, int* __restrict__ es,
                            int* __restrict__ ed, int* __restrict__ cnt, int E,
                            const int* __restrict__ flags, int cb) {
    if ((int)blockIdx.x < cb) {
        int t = blockIdx.x * 256 + threadIdx.x;
        int isf32 = get_isf32(flags);
        if (t < c0) { cast8(s0, d0, t, isf32); return; } t -= c0;
        if (t < c1) { cast8(s1, d1, t, isf32); return; } t -= c1;
        if (t < c2) { cast8(s2, d2, t, isf32); return; } t -= c2;
        if (t < c3) { cast8(s3, d3, t, isf32); return; } t -= c3;
        if (t < c4) { cast8(s4, d4, t, isf32); return; } t -= c4;
        if (t < c5) { cast8(s5, d5, t, isf32); }
    } else {
        int e = (blockIdx.x - cb) * 256 + threadIdx.x;
        if (e >= E) return;
        int sv, dv;
        if (flags[1] == 0) {  // int64
            sv = w[2 * (size_t)e];
            dv = w[2 * (size_t)E + 2 * (size_t)e];
        } else {              // int32
            sv = w[e];
            dv = w[(size_t)E + e];
        }
        es[e] = sv;
        ed[e] = dv;
        atomicAdd(&cnt[dv], 1);
    }
}

// single-block vertical scan: thread-strips + one 1024-wide LDS scan.
__global__ void k_scan(int* __restrict__ cnt, int* __restrict__ row_ptr, int N) {
    __shared__ int part[1024];
    int tid = threadIdx.x;
    int vpt = (N + 1023) >> 10;
    int i0 = tid * vpt;
    int i1 = i0 + vpt; if (i1 > N) i1 = N;
    int s = 0;
    for (int i = i0; i < i1; ++i) s += cnt[i] + 1;
    part[tid] = s;
    __syncthreads();
    for (int off = 1; off < 1024; off <<= 1) {
        int t = (tid >= off) ? part[tid - off] : 0;
        __syncthreads();
        part[tid] += t;
        __syncthreads();
    }
    int run = (tid == 0) ? 0 : part[tid - 1];
    for (int i = i0; i < i1; ++i) {
        int c = cnt[i] + 1;
        cnt[i] = run;            // cursor = exclusive prefix
        run += c;
        row_ptr[i + 1] = run;
    }
    if (tid == 0) row_ptr[0] = 0;
}

// fill CSR: edges via atomic cursor; self-loop of node d at row_ptr[d+1]-1.
__global__ void k_fill(const int* __restrict__ edst, int* __restrict__ cursor,
                       const int* __restrict__ row_ptr, int* __restrict__ csr_e,
                       int E, int N) {
    int e = blockIdx.x * blockDim.x + threadIdx.x;
    if (e < E) {
        int d = edst[e];
        int pos = atomicAdd(&cursor[d], 1);
        csr_e[pos] = e;
    } else if (e < E + N) {
        int d = e - E;
        csr_e[row_ptr[d + 1] - 1] = e;
    }
}

// ---------------------------------------------------------------------------
// Unified MFMA GEMM, split output (both bf16) + fused attention-logit epilogue.
// ---------------------------------------------------------------------------
template<int NT>
__global__ void k_gemm_split(const bf16* __restrict__ A, const bf16* __restrict__ W,
                             const void* __restrict__ bias1, const int* __restrict__ flags,
                             bf16* __restrict__ out0, int S0, int ld0,
                             bf16* __restrict__ out1, int ld1, int n1,
                             int M, int Fo, int K,
                             const void* __restrict__ aS, const void* __restrict__ aD,
                             float* __restrict__ asrc, float* __restrict__ adst, int H) {
    int wid = threadIdx.x >> 6;
    int lane = threadIdx.x & 63;
    int mrow = blockIdx.x * 64 + wid * 16;
    if (mrow >= M) return;
    int ncol = blockIdx.y * (NT * 16);
    int r = lane & 15, g = lane >> 4;

    f32x4 acc[NT];
#pragma unroll
    for (int t = 0; t < NT; ++t) acc[t] = (f32x4){0.f, 0.f, 0.f, 0.f};

    const bf16* arow = A + (size_t)(mrow + r) * K + g * 8;
    const bf16* wbase = W + (size_t)(ncol + r) * K + g * 8;
    for (int k0 = 0; k0 < K; k0 += 32) {
        bf16x8 af = *(const bf16x8*)(arow + k0);
#pragma unroll
        for (int t = 0; t < NT; ++t) {
            bf16x8 bfr = *(const bf16x8*)(wbase + (size_t)t * 16 * K + k0);
            acc[t] = __builtin_amdgcn_mfma_f32_16x16x32_bf16(af, bfr, acc[t], 0, 0, 0);
        }
    }
    int isf32 = get_isf32(flags);

    // main C write
#pragma unroll
    for (int t = 0; t < NT; ++t) {
        int n = ncol + t * 16 + r;
        bool is0 = n < S0;
        int jc = n - S0;
        float bv = (!is0 && jc < n1 && bias1) ? loadf(bias1, jc, isf32) : 0.f;
#pragma unroll
        for (int j = 0; j < 4; ++j) {
            int m = mrow + 4 * g + j;
            float v = acc[t][j] + bv;
            if (is0) out0[(size_t)m * ld0 + n] = __float2bfloat16(v);
            else if (jc < n1) out1[(size_t)m * ld1 + jc] = __float2bfloat16(v);
        }
    }

    // fused alpha epilogue (NT==4 blocks fully inside [0,S0): 2 whole heads)
    if (aS && ncol < S0) {
        float ps[2][4], pd[2][4];
#pragma unroll
        for (int hb = 0; hb < 2; ++hb)
#pragma unroll
            for (int j = 0; j < 4; ++j) { ps[hb][j] = 0.f; pd[hb][j] = 0.f; }
#pragma unroll
        for (int t = 0; t < NT; ++t) {
            int col = ncol + t * 16 + r;
            float asv = loadf(aS, col, isf32);
            float adv = loadf(aD, col, isf32);
#pragma unroll
            for (int j = 0; j < 4; ++j) {
                ps[t >> 1][j] += acc[t][j] * asv;
                pd[t >> 1][j] += acc[t][j] * adv;
            }
        }
#pragma unroll
        for (int mk = 1; mk <= 8; mk <<= 1) {
#pragma unroll
            for (int hb = 0; hb < 2; ++hb)
#pragma unroll
                for (int j = 0; j < 4; ++j) {
                    ps[hb][j] += __shfl_xor(ps[hb][j], mk);
                    pd[hb][j] += __shfl_xor(pd[hb][j], mk);
                }
        }
        if (r == 0) {
            int hA = ncol >> 5, hB = hA + 1;
#pragma unroll
            for (int j = 0; j < 4; ++j) {
                int m = mrow + 4 * g + j;
                asrc[(size_t)m * H + hA] = ps[0][j];
                asrc[(size_t)m * H + hB] = ps[1][j];
                adst[(size_t)m * H + hA] = pd[0][j];
                adst[(size_t)m * H + hB] = pd[1][j];
            }
        }
    }
}

// ---------------------------------------------------------------------------
// Fused per-dst-node softmax + aggregation. One wave per dst node, 4 waves/blk.
// Gathers are 4-edge-parallel (16 lanes/edge) AND unroll-2 over the edge
// stride (edges p and p+4 in flight) => 4 (mode1) / 10 (mode2) independent
// loads per lane. ident bf16. Degree > CAP: slow recompute path.
// ---------------------------------------------------------------------------
#define CAP 96
__global__ void k_fused_agg(const bf16* __restrict__ hlin,
                            const float* __restrict__ asrc, const float* __restrict__ adst,
                            const int* __restrict__ esrc, const int* __restrict__ row_ptr,
                            const int* __restrict__ csr_e,
                            const void* __restrict__ bias, const bf16* __restrict__ identb,
                            void* __restrict__ out, bf16* __restrict__ outb,
                            const int* __restrict__ flags,
                            int E, int N, int H, int mode) {
    __shared__ float el[4][CAP * 10];   // logits -> exp weights; scratch in mode 2
    __shared__ int   ssrc[4][CAP];
    __shared__ float idn[4][10];
    int wid = threadIdx.x >> 6, lane = threadIdx.x & 63;
    int d = blockIdx.x * 4 + wid;
    bool active = d < N;
    int isf32 = get_isf32(flags);
    int F = H * 32;
    int nj = (F + 255) >> 8;
    int lo = 0, deg = 0;
    if (active) { lo = row_ptr[d]; deg = row_ptr[d + 1] - lo; }
    bool fast = deg <= CAP;

    // ---- Pass A: logits into LDS ----
    if (active && fast) {
        int EC = 64 / H;
        int h = lane % H, ei = lane / H;
        float ad = adst[(size_t)d * H + h];
        for (int base = 0; base < deg; base += EC) {
            int p = base + ei;
            if (ei < EC && p < deg) {
                int e = csr_e[lo + p];
                int s = (e < E) ? esrc[e] : (e - E);
                float v = asrc[(size_t)s * H + h] + ad;
                v = (v > 0.f) ? v : 0.2f * v;
                el[wid][p * H + h] = v;
                if (h == 0) ssrc[wid][p] = s;
            }
        }
    }
    __syncthreads();
    // ---- Pass M: per-head softmax normalization ----
    if (active && fast) {
        if (H == 8) {
            int h = lane & 7, sub = lane >> 3;
            float m = -1e30f;
            for (int p = sub; p < deg; p += 8) m = fmaxf(m, el[wid][p * 8 + h]);
            m = fmaxf(m, __shfl_xor(m, 8));
            m = fmaxf(m, __shfl_xor(m, 16));
            m = fmaxf(m, __shfl_xor(m, 32));
            float den = 0.f;
            for (int p = sub; p < deg; p += 8) {
                float t = __expf(el[wid][p * 8 + h] - m);
                el[wid][p * 8 + h] = t;
                den += t;
            }
            den += __shfl_xor(den, 8);
            den += __shfl_xor(den, 16);
            den += __shfl_xor(den, 32);
            if (lane < 8) idn[wid][lane] = 1.f / (den + 1e-16f);
        } else if (lane < H) {
            float m = -1e30f;
            for (int p = 0; p < deg; ++p) m = fmaxf(m, el[wid][p * H + lane]);
            float den = 0.f;
            for (int p = 0; p < deg; ++p) {
                float t = __expf(el[wid][p * H + lane] - m);
                el[wid][p * H + lane] = t;
                den += t;
            }
            idn[wid][lane] = 1.f / (den + 1e-16f);
        }
    }
    __syncthreads();
    if (!active) return;

    if (mode == 1 && fast) {
        // ---- F=256, H=8: 4-edge-parallel, unroll-2 (edges p, p+4) ----
        int g = lane & 15, q = lane >> 4;
        int f0 = g * 16;
        f32x4 a0 = {0.f,0.f,0.f,0.f}, a1 = {0.f,0.f,0.f,0.f};
        f32x4 a2 = {0.f,0.f,0.f,0.f}, a3 = {0.f,0.f,0.f,0.f};
        int p = q;
        for (; p + 4 < deg; p += 8) {
            int s0 = ssrc[wid][p];
            int s1 = ssrc[wid][p + 4];
            const bf16* hp0 = hlin + (size_t)s0 * 256 + f0;
            const bf16* hp1 = hlin + (size_t)s1 * 256 + f0;
            bf16x8 u0 = *(const bf16x8*)hp0;
            bf16x8 u1 = *(const bf16x8*)(hp0 + 8);
            bf16x8 v0 = *(const bf16x8*)hp1;
            bf16x8 v1 = *(const bf16x8*)(hp1 + 8);
            float w0 = el[wid][p * 8 + (g >> 1)];
            float w1 = el[wid][(p + 4) * 8 + (g >> 1)];
#pragma unroll
            for (int k = 0; k < 4; ++k) {
                a0[k] += w0 * bf2fs(u0[k]);
                a1[k] += w0 * bf2fs(u0[4 + k]);
                a2[k] += w0 * bf2fs(u1[k]);
                a3[k] += w0 * bf2fs(u1[4 + k]);
                a0[k] += w1 * bf2fs(v0[k]);
                a1[k] += w1 * bf2fs(v0[4 + k]);
                a2[k] += w1 * bf2fs(v1[k]);
                a3[k] += w1 * bf2fs(v1[4 + k]);
            }
        }
        if (p < deg) {
            int s0 = ssrc[wid][p];
            const bf16* hp0 = hlin + (size_t)s0 * 256 + f0;
            bf16x8 u0 = *(const bf16x8*)hp0;
            bf16x8 u1 = *(const bf16x8*)(hp0 + 8);
            float w0 = el[wid][p * 8 + (g >> 1)];
#pragma unroll
            for (int k = 0; k < 4; ++k) {
                a0[k] += w0 * bf2fs(u0[k]);
                a1[k] += w0 * bf2fs(u0[4 + k]);
                a2[k] += w0 * bf2fs(u1[k]);
                a3[k] += w0 * bf2fs(u1[4 + k]);
            }
        }
#pragma unroll
        for (int k = 0; k < 4; ++k) {
            a0[k] += __shfl_xor(a0[k], 16); a1[k] += __shfl_xor(a1[k], 16);
            a2[k] += __shfl_xor(a2[k], 16); a3[k] += __shfl_xor(a3[k], 16);
            a0[k] += __shfl_xor(a0[k], 32); a1[k] += __shfl_xor(a1[k], 32);
            a2[k] += __shfl_xor(a2[k], 32); a3[k] += __shfl_xor(a3[k], 32);
        }
        if (lane < 16) {
            float inv = idn[wid][g >> 1];
            const bf16* idp = identb + (size_t)d * 256 + f0;
            bf16x8 id0 = *(const bf16x8*)idp;
            bf16x8 id1 = *(const bf16x8*)(idp + 8);
            bf16* ob = outb + (size_t)d * 256 + f0;
            f32x4 av[4] = {a0, a1, a2, a3};
            bf16x8 obv0, obv1;
#pragma unroll
            for (int i = 0; i < 4; ++i) {
#pragma unroll
                for (int k = 0; k < 4; ++k) {
                    float v = av[i][k] * inv + loadf(bias, f0 + 4 * i + k, isf32);
                    v = (v > 0.f) ? v : (__expf(v) - 1.f);  // ELU
                    int e8 = 4 * i + k;
                    v += bf2fs((e8 < 8) ? id0[e8] : id1[e8 - 8]);
                    if (i < 2) obv0[e8] = f2bfs(v);
                    else       obv1[e8 - 8] = f2bfs(v);
                }
            }
            *(bf16x8*)ob = obv0;
            *(bf16x8*)(ob + 8) = obv1;
        }
        return;
    }

    if (mode == 2 && fast) {
        // ---- F=320, H=10: 4-edge-parallel, unroll-2 ----
        int g = lane & 15, q = lane >> 4;
        int f0 = g * 16;
        int f1 = 256 + g * 4;
        f32x4 a0 = {0.f,0.f,0.f,0.f}, a1 = {0.f,0.f,0.f,0.f};
        f32x4 a2 = {0.f,0.f,0.f,0.f}, a3 = {0.f,0.f,0.f,0.f};
        f32x4 a4 = {0.f,0.f,0.f,0.f};
        int p = q;
        for (; p + 4 < deg; p += 8) {
            int s0 = ssrc[wid][p];
            int s1 = ssrc[wid][p + 4];
            const bf16* hp0 = hlin + (size_t)s0 * 320;
            const bf16* hp1 = hlin + (size_t)s1 * 320;
            bf16x8 u0 = *(const bf16x8*)(hp0 + f0);
            bf16x8 u1 = *(const bf16x8*)(hp0 + f0 + 8);
            bf16x4 u2 = *(const bf16x4*)(hp0 + f1);
            bf16x8 v0 = *(const bf16x8*)(hp1 + f0);
            bf16x8 v1 = *(const bf16x8*)(hp1 + f0 + 8);
            bf16x4 v2 = *(const bf16x4*)(hp1 + f1);
            float w00 = el[wid][p * 10 + (g >> 1)];
            float w02 = el[wid][p * 10 + 8 + (g >> 3)];
            float w10 = el[wid][(p + 4) * 10 + (g >> 1)];
            float w12 = el[wid][(p + 4) * 10 + 8 + (g >> 3)];
#pragma unroll
            for (int k = 0; k < 4; ++k) {
                a0[k] += w00 * bf2fs(u0[k]);
                a1[k] += w00 * bf2fs(u0[4 + k]);
                a2[k] += w00 * bf2fs(u1[k]);
                a3[k] += w00 * bf2fs(u1[4 + k]);
                a4[k] += w02 * bf2fs(u2[k]);
                a0[k] += w10 * bf2fs(v0[k]);
                a1[k] += w10 * bf2fs(v0[4 + k]);
                a2[k] += w10 * bf2fs(v1[k]);
                a3[k] += w10 * bf2fs(v1[4 + k]);
                a4[k] += w12 * bf2fs(v2[k]);
            }
        }
        if (p < deg) {
            int s0 = ssrc[wid][p];
            const bf16* hp0 = hlin + (size_t)s0 * 320;
            bf16x8 u0 = *(const bf16x8*)(hp0 + f0);
            bf16x8 u1 = *(const bf16x8*)(hp0 + f0 + 8);
            bf16x4 u2 = *(const bf16x4*)(hp0 + f1);
            float w00 = el[wid][p * 10 + (g >> 1)];
            float w02 = el[wid][p * 10 + 8 + (g >> 3)];
#pragma unroll
            for (int k = 0; k < 4; ++k) {
                a0[k] += w00 * bf2fs(u0[k]);
                a1[k] += w00 * bf2fs(u0[4 + k]);
                a2[k] += w00 * bf2fs(u1[k]);
                a3[k] += w00 * bf2fs(u1[4 + k]);
                a4[k] += w02 * bf2fs(u2[k]);
            }
        }
#pragma unroll
        for (int k = 0; k < 4; ++k) {
            a0[k] += __shfl_xor(a0[k], 16); a1[k] += __shfl_xor(a1[k], 16);
            a2[k] += __shfl_xor(a2[k], 16); a3[k] += __shfl_xor(a3[k], 16);
            a4[k] += __shfl_xor(a4[k], 16);
            a0[k] += __shfl_xor(a0[k], 32); a1[k] += __shfl_xor(a1[k], 32);
            a2[k] += __shfl_xor(a2[k], 32); a3[k] += __shfl_xor(a3[k], 32);
            a4[k] += __shfl_xor(a4[k], 32);
        }
        float* scratch = &el[wid][0];
        if (lane < 16) {
            float inv0 = idn[wid][g >> 1];
            float inv2 = idn[wid][8 + (g >> 3)];
#pragma unroll
            for (int k = 0; k < 4; ++k) {
                scratch[f0 + k]      = a0[k] * inv0;
                scratch[f0 + 4 + k]  = a1[k] * inv0;
                scratch[f0 + 8 + k]  = a2[k] * inv0;
                scratch[f0 + 12 + k] = a3[k] * inv0;
                scratch[f1 + k]      = a4[k] * inv2;
            }
        }
        if (lane < 32) {
            float s = 0.f;
#pragma unroll
            for (int h = 0; h < 10; ++h) s += scratch[h * 32 + lane];
            float v = s * 0.1f + loadf(bias, lane, isf32)
                    + bf2f(identb[(size_t)d * 32 + lane]);
            if (isf32) ((float*)out)[(size_t)d * 32 + lane] = v;
            else ((bf16*)out)[(size_t)d * 32 + lane] = __float2bfloat16(v);
        }
        return;
    }

    // ---- slow path (deg > CAP): recompute logits per lane-channel-group ----
    f32x4 acc[2] = {(f32x4){0.f,0.f,0.f,0.f}, (f32x4){0.f,0.f,0.f,0.f}};
    for (int j = 0; j < nj; ++j) {
        int f0 = (lane + 64 * j) * 4;
        if (f0 >= F) continue;
        int hj = f0 >> 5;
        float ad = adst[(size_t)d * H + hj];
        float m = -1e30f;
        for (int p = 0; p < deg; ++p) {
            int e = csr_e[lo + p];
            int s = (e < E) ? esrc[e] : (e - E);
            float v = asrc[(size_t)s * H + hj] + ad;
            v = (v > 0.f) ? v : 0.2f * v;
            m = fmaxf(m, v);
        }
        float den = 0.f;
        f32x4 a4 = {0.f, 0.f, 0.f, 0.f};
        for (int p = 0; p < deg; ++p) {
            int e = csr_e[lo + p];
            int s = (e < E) ? esrc[e] : (e - E);
            float v = asrc[(size_t)s * H + hj] + ad;
            v = (v > 0.f) ? v : 0.2f * v;
            float t = __expf(v - m);
            den += t;
            bf16x4 hv = *(const bf16x4*)(hlin + (size_t)s * F + f0);
            for (int k = 0; k < 4; ++k) a4[k] += t * bf2fs(hv[k]);
        }
        float inv = 1.f / (den + 1e-16f);
        for (int k = 0; k < 4; ++k) acc[j][k] = a4[k] * inv;
    }
    if (mode == 1) {
        int f0 = lane * 4;
        bf16x4 ob;
#pragma unroll
        for (int k = 0; k < 4; ++k) {
            float v = acc[0][k] + loadf(bias, f0 + k, isf32);
            v = (v > 0.f) ? v : (__expf(v) - 1.f);
            v += bf2f(identb[(size_t)d * F + f0 + k]);
            ob[k] = f2bfs(v);
        }
        *(bf16x4*)(outb + (size_t)d * F + f0) = ob;
    } else {
        float* scratch = &el[wid][0];
#pragma unroll
        for (int j = 0; j < 2; ++j) {
            int f0 = (lane + 64 * j) * 4;
            if (j < nj && f0 < F) {
#pragma unroll
                for (int k = 0; k < 4; ++k) scratch[f0 + k] = acc[j][k];
            }
        }
        if (lane < 32) {
            float s = 0.f;
            for (int h = 0; h < H; ++h) s += scratch[h * 32 + lane];
            float v = s * (1.f / (float)H) + loadf(bias, lane, isf32)
                    + bf2f(identb[(size_t)d * 32 + lane]);
            if (isf32) ((float*)out)[(size_t)d * 32 + lane] = v;
            else ((bf16*)out)[(size_t)d * 32 + lane] = __float2bfloat16(v);
        }
    }
}

extern "C" void kernel_launch(void* const* d_in, const int* in_sizes, int n_in,
                              void* d_out, int out_size, void* d_ws, size_t ws_size,
                              hipStream_t stream) {
    const int IN = 256, C = 32;
    const int N = in_sizes[0] / IN;
    const int E = in_sizes[1] / 2;
    const int ET = E + N;

    const void* x    = d_in[0];
    const int*  edge = (const int*)d_in[1];
    const void* W1 = d_in[2];
    const void* a1s = d_in[3];
    const void* a1d = d_in[4];
    const void* b1 = d_in[5];
    const void* W2 = d_in[6];
    const void* a2s = d_in[7];
    const void* a2d = d_in[8];
    const void* b2 = d_in[9];
    const void* W3 = d_in[10];
    const void* a3s = d_in[11];
    const void* a3d = d_in[12];
    const void* b3 = d_in[13];
    const void* P1W = d_in[14];
    const void* P1b = d_in[15];
    const void* P3W = d_in[16];
    const void* P3b = d_in[17];

    char* ws = (char*)d_ws;
    size_t off = 0;
    auto alloc = [&](size_t bytes) -> void* {
        void* p = ws + off;
        off = (off + bytes + 255) & ~(size_t)255;
        return p;
    };
    bf16* fxb   = (bf16*)alloc((size_t)N * 256 * 2);    // bf16 input
    bf16* fyb   = (bf16*)alloc((size_t)N * 256 * 2);    // bf16 layer outputs
    bf16* fhb   = (bf16*)alloc((size_t)N * 320 * 2);    // h_lin bf16 (per layer)
    bf16* fidb  = (bf16*)alloc((size_t)N * 256 * 2);    // identity1 / identity3 (bf16)
    float* fasrc = (float*)alloc((size_t)N * 10 * 4);
    float* fadst = (float*)alloc((size_t)N * 10 * 4);
    bf16* wc1   = (bf16*)alloc((size_t)512 * 256 * 2);  // [W1; P1W]
    bf16* wb2   = (bf16*)alloc((size_t)256 * 256 * 2);
    bf16* wc3   = (bf16*)alloc((size_t)384 * 256 * 2);  // [W3; P3W; 32 pad rows]
    int*  isrc  = (int*)alloc((size_t)E * 4);
    int*  idst  = (int*)alloc((size_t)E * 4);
    int*  irow  = (int*)alloc((size_t)(N + 1) * 4);
    int*  icur  = (int*)alloc((size_t)N * 4);
    int*  icsr  = (int*)alloc((size_t)ET * 4);
    int*  flags = (int*)alloc(4 * 4);
    (void)ws_size;

    auto cdiv = [](int a, int b) { return (a + b - 1) / b; };

    // init: block0 = dtype detection (prefix probe), rest zero degree counters
    int nprobe_x = (N * 256 < 16384) ? N * 256 : 16384;
    int nprobe_e = (2 * E < 8192) ? 2 * E : 8192;
    k_init<<<1 + cdiv(N, 256), 256, 0, stream>>>(
        (const unsigned short*)x, edge, flags, icur, N, nprobe_x, nprobe_e);

    // casts + edge normalize + degree count in one launch
    int c_x = N * 256 / 8, c_w = 256 * 256 / 8, c_w3 = 320 * 256 / 8, c_p3 = 32 * 256 / 8;
    int ctot = c_x + 3 * c_w + c_w3 + c_p3;
    int cb = cdiv(ctot, 256);
    k_cast_norm<<<cb + cdiv(E, 256), 256, 0, stream>>>(
        x, fxb, c_x,
        W1, wc1, c_w,
        P1W, wc1 + (size_t)256 * 256, c_w,
        W2, wb2, c_w,
        W3, wc3, c_w3,
        P3W, wc3 + (size_t)320 * 256, c_p3,
        edge, isrc, idst, icur, E, flags, cb);

    k_scan<<<1, 1024, 0, stream>>>(icur, irow, N);
    k_fill<<<cdiv(ET, 256), 256, 0, stream>>>(idst, icur, irow, icsr, E, N);

    int gx = cdiv(N, 64);
    int ga = cdiv(N, 4);

    // ---- Layer 1: H=8; combined [W1;P1W] GEMM + fused alpha ----
    {
        int H = 8;
        k_gemm_split<4><<<dim3(gx, 8), 256, 0, stream>>>(
            fxb, wc1, P1b, flags, fhb, 256, 256, fidb, 256, 256, N, 512, 256,
            a1s, a1d, fasrc, fadst, H);
        k_fused_agg<<<ga, 256, 0, stream>>>(fhb, fasrc, fadst, isrc, irow, icsr,
                                            b1, fidb, nullptr, fyb, flags, E, N, H, 1);
    }
    // ---- Layer 2: H=8, identity = layer-1 output (bf16, in-place) ----
    {
        int H = 8;
        k_gemm_split<4><<<dim3(gx, 4), 256, 0, stream>>>(
            fyb, wb2, nullptr, flags, fhb, 256, 256, nullptr, 0, 0, N, 256, 256,
            a2s, a2d, fasrc, fadst, H);
        k_fused_agg<<<ga, 256, 0, stream>>>(fhb, fasrc, fadst, isrc, irow, icsr,
                                            b2, fyb, nullptr, fyb, flags, E, N, H, 1);
    }
    // ---- Layer 3: H=10, concat=False; combined [W3;P3W;pad] GEMM ----
    {
        int H = 10;
        k_gemm_split<4><<<dim3(gx, 6), 256, 0, stream>>>(
            fyb, wc3, P3b, flags, fhb, 320, 320, fidb, 32, 32, N, 384, 256,
            a3s, a3d, fasrc, fadst, H);
        k_fused_agg<<<ga, 256, 0, stream>>>(fhb, fasrc, fadst, isrc, irow, icsr,
                                            b3, fidb, d_out, nullptr, flags, E, N, H, 2);
    }
}

// Round 12
// 201.679 us; speedup vs baseline: 1.0941x; 1.0941x over previous
//
#include <hip/hip_runtime.h>
#include <hip/hip_bf16.h>

typedef __hip_bfloat16 bf16;
typedef __attribute__((ext_vector_type(8))) short bf16x8;
typedef __attribute__((ext_vector_type(4))) short bf16x4;
typedef __attribute__((ext_vector_type(4))) float f32x4;

// ---------------------------------------------------------------------------
// 3-layer GAT forward. Dtype-adaptive (observed world: floats=bf16, edges=i32).
// flags[0]=1 if NaN/Inf ushort pattern in x-prefix (=> x is f32)
// flags[1]=1 if any odd 32-bit word of edge prefix nonzero (=> edges i32)
// flags[2]=1 if any even-index ushort of x-prefix nonzero
// isf32 = flags[0] || !flags[2]
// NOTE (r11 lesson): detection must be MULTI-block — a single block probing
// 24K elements serializes ~96 cold-HBM loads => 40 µs latency chain.
// ---------------------------------------------------------------------------

static __device__ __forceinline__ float bf2f(bf16 v) { return __bfloat162float(v); }
static __device__ __forceinline__ float bf2fs(short v) {
    unsigned int u = ((unsigned int)(unsigned short)v) << 16;
    return __builtin_bit_cast(float, u);
}
static __device__ __forceinline__ short f2bfs(float f) {
    bf16 b = __float2bfloat16(f);
    return __builtin_bit_cast(short, b);
}
static __device__ __forceinline__ float loadf(const void* p, size_t i, int isf32) {
    return isf32 ? ((const float*)p)[i] : bf2f(((const bf16*)p)[i]);
}
static __device__ __forceinline__ int get_isf32(const int* flags) {
    return (flags[0] | (flags[2] == 0)) ? 1 : 0;
}

// zero flags[4] + cnt[N]
__global__ void k_zero(int* __restrict__ flags, int* __restrict__ cnt, int N) {
    int i = blockIdx.x * blockDim.x + threadIdx.x;
    if (i < 4) flags[i] = 0;
    for (; i < N; i += gridDim.x * blockDim.x) cnt[i] = 0;
}

// detection: tiny probe spread over many blocks, LDS aggregation, <=3 atomics/blk
__global__ void k_detect(const unsigned short* __restrict__ xu, const int* __restrict__ ew,
                         int* __restrict__ flags, int nx, int ne2, int bx) {
    __shared__ int lf[3];
    if (threadIdx.x < 3) lf[threadIdx.x] = 0;
    __syncthreads();
    if ((int)blockIdx.x < bx) {
        for (int i = blockIdx.x * 256 + threadIdx.x; i < nx; i += bx * 256) {
            unsigned short v = xu[i];
            if ((v & 0x7F80u) == 0x7F80u) lf[0] = 1;
            if (((i & 1) == 0) && v != 0) lf[2] = 1;
        }
    } else {
        int nb = gridDim.x - bx;
        for (int i = (blockIdx.x - bx) * 256 + threadIdx.x; i < ne2; i += nb * 256) {
            if ((i & 1) && ew[i] != 0) lf[1] = 1;
        }
    }
    __syncthreads();
    if (threadIdx.x == 0) {
        if (lf[0]) atomicOr(&flags[0], 1);
        if (lf[1]) atomicOr(&flags[1], 1);
        if (lf[2]) atomicOr(&flags[2], 1);
    }
}

// 8-elem vectorized adaptive cast
static __device__ __forceinline__ void cast8(const void* src, bf16* dst, int i8, int isf32) {
    if (isf32) {
        f32x4 a = ((const f32x4*)src)[2 * i8];
        f32x4 b = ((const f32x4*)src)[2 * i8 + 1];
        bf16x8 o;
        o[0] = f2bfs(a[0]); o[1] = f2bfs(a[1]); o[2] = f2bfs(a[2]); o[3] = f2bfs(a[3]);
        o[4] = f2bfs(b[0]); o[5] = f2bfs(b[1]); o[6] = f2bfs(b[2]); o[7] = f2bfs(b[3]);
        ((bf16x8*)dst)[i8] = o;
    } else {
        ((bf16x8*)dst)[i8] = ((const bf16x8*)src)[i8];
    }
}

// blocks [0, cb): all input casts (counts in 8-elem units).
// blocks [cb, ...): edge normalize + degree count.
__global__ void k_cast_norm(const void* s0, bf16* d0, int c0,
                            const void* s1, bf16* d1, int c1,
                            const void* s2, bf16* d2, int c2,
                            const void* s3, bf16* d3, int c3,
                            const void* s4, bf16* d4, int c4,
                            const void* s5, bf16* d5, int c5,
                            const int* __restrict__ w, int* __restrict__ es,
                            int* __restrict__ ed, int* __restrict__ cnt, int E,
                            const int* __restrict__ flags, int cb) {
    if ((int)blockIdx.x < cb) {
        int t = blockIdx.x * 256 + threadIdx.x;
        int isf32 = get_isf32(flags);
        if (t < c0) { cast8(s0, d0, t, isf32); return; } t -= c0;
        if (t < c1) { cast8(s1, d1, t, isf32); return; } t -= c1;
        if (t < c2) { cast8(s2, d2, t, isf32); return; } t -= c2;
        if (t < c3) { cast8(s3, d3, t, isf32); return; } t -= c3;
        if (t < c4) { cast8(s4, d4, t, isf32); return; } t -= c4;
        if (t < c5) { cast8(s5, d5, t, isf32); }
    } else {
        int e = (blockIdx.x - cb) * 256 + threadIdx.x;
        if (e >= E) return;
        int sv, dv;
        if (flags[1] == 0) {  // int64
            sv = w[2 * (size_t)e];
            dv = w[2 * (size_t)E + 2 * (size_t)e];
        } else {              // int32
            sv = w[e];
            dv = w[(size_t)E + e];
        }
        es[e] = sv;
        ed[e] = dv;
        atomicAdd(&cnt[dv], 1);
    }
}

// single-block vertical scan: thread-strips + one 1024-wide LDS scan.
__global__ void k_scan(int* __restrict__ cnt, int* __restrict__ row_ptr, int N) {
    __shared__ int part[1024];
    int tid = threadIdx.x;
    int vpt = (N + 1023) >> 10;
    int i0 = tid * vpt;
    int i1 = i0 + vpt; if (i1 > N) i1 = N;
    int s = 0;
    for (int i = i0; i < i1; ++i) s += cnt[i] + 1;
    part[tid] = s;
    __syncthreads();
    for (int off = 1; off < 1024; off <<= 1) {
        int t = (tid >= off) ? part[tid - off] : 0;
        __syncthreads();
        part[tid] += t;
        __syncthreads();
    }
    int run = (tid == 0) ? 0 : part[tid - 1];
    for (int i = i0; i < i1; ++i) {
        int c = cnt[i] + 1;
        cnt[i] = run;            // cursor = exclusive prefix
        run += c;
        row_ptr[i + 1] = run;
    }
    if (tid == 0) row_ptr[0] = 0;
}

// fill CSR: edges via atomic cursor; self-loop of node d at row_ptr[d+1]-1.
__global__ void k_fill(const int* __restrict__ edst, int* __restrict__ cursor,
                       const int* __restrict__ row_ptr, int* __restrict__ csr_e,
                       int E, int N) {
    int e = blockIdx.x * blockDim.x + threadIdx.x;
    if (e < E) {
        int d = edst[e];
        int pos = atomicAdd(&cursor[d], 1);
        csr_e[pos] = e;
    } else if (e < E + N) {
        int d = e - E;
        csr_e[row_ptr[d + 1] - 1] = e;
    }
}

// ---------------------------------------------------------------------------
// Unified MFMA GEMM, split output (both bf16) + fused attention-logit epilogue.
// ---------------------------------------------------------------------------
template<int NT>
__global__ void k_gemm_split(const bf16* __restrict__ A, const bf16* __restrict__ W,
                             const void* __restrict__ bias1, const int* __restrict__ flags,
                             bf16* __restrict__ out0, int S0, int ld0,
                             bf16* __restrict__ out1, int ld1, int n1,
                             int M, int Fo, int K,
                             const void* __restrict__ aS, const void* __restrict__ aD,
                             float* __restrict__ asrc, float* __restrict__ adst, int H) {
    int wid = threadIdx.x >> 6;
    int lane = threadIdx.x & 63;
    int mrow = blockIdx.x * 64 + wid * 16;
    if (mrow >= M) return;
    int ncol = blockIdx.y * (NT * 16);
    int r = lane & 15, g = lane >> 4;

    f32x4 acc[NT];
#pragma unroll
    for (int t = 0; t < NT; ++t) acc[t] = (f32x4){0.f, 0.f, 0.f, 0.f};

    const bf16* arow = A + (size_t)(mrow + r) * K + g * 8;
    const bf16* wbase = W + (size_t)(ncol + r) * K + g * 8;
    for (int k0 = 0; k0 < K; k0 += 32) {
        bf16x8 af = *(const bf16x8*)(arow + k0);
#pragma unroll
        for (int t = 0; t < NT; ++t) {
            bf16x8 bfr = *(const bf16x8*)(wbase + (size_t)t * 16 * K + k0);
            acc[t] = __builtin_amdgcn_mfma_f32_16x16x32_bf16(af, bfr, acc[t], 0, 0, 0);
        }
    }
    int isf32 = get_isf32(flags);

    // main C write
#pragma unroll
    for (int t = 0; t < NT; ++t) {
        int n = ncol + t * 16 + r;
        bool is0 = n < S0;
        int jc = n - S0;
        float bv = (!is0 && jc < n1 && bias1) ? loadf(bias1, jc, isf32) : 0.f;
#pragma unroll
        for (int j = 0; j < 4; ++j) {
            int m = mrow + 4 * g + j;
            float v = acc[t][j] + bv;
            if (is0) out0[(size_t)m * ld0 + n] = __float2bfloat16(v);
            else if (jc < n1) out1[(size_t)m * ld1 + jc] = __float2bfloat16(v);
        }
    }

    // fused alpha epilogue (NT==4 blocks fully inside [0,S0): 2 whole heads)
    if (aS && ncol < S0) {
        float ps[2][4], pd[2][4];
#pragma unroll
        for (int hb = 0; hb < 2; ++hb)
#pragma unroll
            for (int j = 0; j < 4; ++j) { ps[hb][j] = 0.f; pd[hb][j] = 0.f; }
#pragma unroll
        for (int t = 0; t < NT; ++t) {
            int col = ncol + t * 16 + r;
            float asv = loadf(aS, col, isf32);
            float adv = loadf(aD, col, isf32);
#pragma unroll
            for (int j = 0; j < 4; ++j) {
                ps[t >> 1][j] += acc[t][j] * asv;
                pd[t >> 1][j] += acc[t][j] * adv;
            }
        }
#pragma unroll
        for (int mk = 1; mk <= 8; mk <<= 1) {
#pragma unroll
            for (int hb = 0; hb < 2; ++hb)
#pragma unroll
                for (int j = 0; j < 4; ++j) {
                    ps[hb][j] += __shfl_xor(ps[hb][j], mk);
                    pd[hb][j] += __shfl_xor(pd[hb][j], mk);
                }
        }
        if (r == 0) {
            int hA = ncol >> 5, hB = hA + 1;
#pragma unroll
            for (int j = 0; j < 4; ++j) {
                int m = mrow + 4 * g + j;
                asrc[(size_t)m * H + hA] = ps[0][j];
                asrc[(size_t)m * H + hB] = ps[1][j];
                adst[(size_t)m * H + hA] = pd[0][j];
                adst[(size_t)m * H + hB] = pd[1][j];
            }
        }
    }
}

// ---------------------------------------------------------------------------
// Fused per-dst-node softmax + aggregation. One wave per dst node, 4 waves/blk.
// Gathers are 4-edge-parallel (16 lanes/edge) AND unroll-2 over the edge
// stride (edges p and p+4 in flight). ident bf16. Degree > CAP: slow path.
// ---------------------------------------------------------------------------
#define CAP 96
__global__ void k_fused_agg(const bf16* __restrict__ hlin,
                            const float* __restrict__ asrc, const float* __restrict__ adst,
                            const int* __restrict__ esrc, const int* __restrict__ row_ptr,
                            const int* __restrict__ csr_e,
                            const void* __restrict__ bias, const bf16* __restrict__ identb,
                            void* __restrict__ out, bf16* __restrict__ outb,
                            const int* __restrict__ flags,
                            int E, int N, int H, int mode) {
    __shared__ float el[4][CAP * 10];   // logits -> exp weights; scratch in mode 2
    __shared__ int   ssrc[4][CAP];
    __shared__ float idn[4][10];
    int wid = threadIdx.x >> 6, lane = threadIdx.x & 63;
    int d = blockIdx.x * 4 + wid;
    bool active = d < N;
    int isf32 = get_isf32(flags);
    int F = H * 32;
    int nj = (F + 255) >> 8;
    int lo = 0, deg = 0;
    if (active) { lo = row_ptr[d]; deg = row_ptr[d + 1] - lo; }
    bool fast = deg <= CAP;

    // ---- Pass A: logits into LDS ----
    if (active && fast) {
        int EC = 64 / H;
        int h = lane % H, ei = lane / H;
        float ad = adst[(size_t)d * H + h];
        for (int base = 0; base < deg; base += EC) {
            int p = base + ei;
            if (ei < EC && p < deg) {
                int e = csr_e[lo + p];
                int s = (e < E) ? esrc[e] : (e - E);
                float v = asrc[(size_t)s * H + h] + ad;
                v = (v > 0.f) ? v : 0.2f * v;
                el[wid][p * H + h] = v;
                if (h == 0) ssrc[wid][p] = s;
            }
        }
    }
    __syncthreads();
    // ---- Pass M: per-head softmax normalization ----
    if (active && fast) {
        if (H == 8) {
            int h = lane & 7, sub = lane >> 3;
            float m = -1e30f;
            for (int p = sub; p < deg; p += 8) m = fmaxf(m, el[wid][p * 8 + h]);
            m = fmaxf(m, __shfl_xor(m, 8));
            m = fmaxf(m, __shfl_xor(m, 16));
            m = fmaxf(m, __shfl_xor(m, 32));
            float den = 0.f;
            for (int p = sub; p < deg; p += 8) {
                float t = __expf(el[wid][p * 8 + h] - m);
                el[wid][p * 8 + h] = t;
                den += t;
            }
            den += __shfl_xor(den, 8);
            den += __shfl_xor(den, 16);
            den += __shfl_xor(den, 32);
            if (lane < 8) idn[wid][lane] = 1.f / (den + 1e-16f);
        } else if (lane < H) {
            float m = -1e30f;
            for (int p = 0; p < deg; ++p) m = fmaxf(m, el[wid][p * H + lane]);
            float den = 0.f;
            for (int p = 0; p < deg; ++p) {
                float t = __expf(el[wid][p * H + lane] - m);
                el[wid][p * H + lane] = t;
                den += t;
            }
            idn[wid][lane] = 1.f / (den + 1e-16f);
        }
    }
    __syncthreads();
    if (!active) return;

    if (mode == 1 && fast) {
        // ---- F=256, H=8: 4-edge-parallel, unroll-2 (edges p, p+4) ----
        int g = lane & 15, q = lane >> 4;
        int f0 = g * 16;
        f32x4 a0 = {0.f,0.f,0.f,0.f}, a1 = {0.f,0.f,0.f,0.f};
        f32x4 a2 = {0.f,0.f,0.f,0.f}, a3 = {0.f,0.f,0.f,0.f};
        int p = q;
        for (; p + 4 < deg; p += 8) {
            int s0 = ssrc[wid][p];
            int s1 = ssrc[wid][p + 4];
            const bf16* hp0 = hlin + (size_t)s0 * 256 + f0;
            const bf16* hp1 = hlin + (size_t)s1 * 256 + f0;
            bf16x8 u0 = *(const bf16x8*)hp0;
            bf16x8 u1 = *(const bf16x8*)(hp0 + 8);
            bf16x8 v0 = *(const bf16x8*)hp1;
            bf16x8 v1 = *(const bf16x8*)(hp1 + 8);
            float w0 = el[wid][p * 8 + (g >> 1)];
            float w1 = el[wid][(p + 4) * 8 + (g >> 1)];
#pragma unroll
            for (int k = 0; k < 4; ++k) {
                a0[k] += w0 * bf2fs(u0[k]);
                a1[k] += w0 * bf2fs(u0[4 + k]);
                a2[k] += w0 * bf2fs(u1[k]);
                a3[k] += w0 * bf2fs(u1[4 + k]);
                a0[k] += w1 * bf2fs(v0[k]);
                a1[k] += w1 * bf2fs(v0[4 + k]);
                a2[k] += w1 * bf2fs(v1[k]);
                a3[k] += w1 * bf2fs(v1[4 + k]);
            }
        }
        if (p < deg) {
            int s0 = ssrc[wid][p];
            const bf16* hp0 = hlin + (size_t)s0 * 256 + f0;
            bf16x8 u0 = *(const bf16x8*)hp0;
            bf16x8 u1 = *(const bf16x8*)(hp0 + 8);
            float w0 = el[wid][p * 8 + (g >> 1)];
#pragma unroll
            for (int k = 0; k < 4; ++k) {
                a0[k] += w0 * bf2fs(u0[k]);
                a1[k] += w0 * bf2fs(u0[4 + k]);
                a2[k] += w0 * bf2fs(u1[k]);
                a3[k] += w0 * bf2fs(u1[4 + k]);
            }
        }
#pragma unroll
        for (int k = 0; k < 4; ++k) {
            a0[k] += __shfl_xor(a0[k], 16); a1[k] += __shfl_xor(a1[k], 16);
            a2[k] += __shfl_xor(a2[k], 16); a3[k] += __shfl_xor(a3[k], 16);
            a0[k] += __shfl_xor(a0[k], 32); a1[k] += __shfl_xor(a1[k], 32);
            a2[k] += __shfl_xor(a2[k], 32); a3[k] += __shfl_xor(a3[k], 32);
        }
        if (lane < 16) {
            float inv = idn[wid][g >> 1];
            const bf16* idp = identb + (size_t)d * 256 + f0;
            bf16x8 id0 = *(const bf16x8*)idp;
            bf16x8 id1 = *(const bf16x8*)(idp + 8);
            bf16* ob = outb + (size_t)d * 256 + f0;
            f32x4 av[4] = {a0, a1, a2, a3};
            bf16x8 obv0, obv1;
#pragma unroll
            for (int i = 0; i < 4; ++i) {
#pragma unroll
                for (int k = 0; k < 4; ++k) {
                    float v = av[i][k] * inv + loadf(bias, f0 + 4 * i + k, isf32);
                    v = (v > 0.f) ? v : (__expf(v) - 1.f);  // ELU
                    int e8 = 4 * i + k;
                    v += bf2fs((e8 < 8) ? id0[e8] : id1[e8 - 8]);
                    if (i < 2) obv0[e8] = f2bfs(v);
                    else       obv1[e8 - 8] = f2bfs(v);
                }
            }
            *(bf16x8*)ob = obv0;
            *(bf16x8*)(ob + 8) = obv1;
        }
        return;
    }

    if (mode == 2 && fast) {
        // ---- F=320, H=10: 4-edge-parallel, unroll-2 ----
        int g = lane & 15, q = lane >> 4;
        int f0 = g * 16;
        int f1 = 256 + g * 4;
        f32x4 a0 = {0.f,0.f,0.f,0.f}, a1 = {0.f,0.f,0.f,0.f};
        f32x4 a2 = {0.f,0.f,0.f,0.f}, a3 = {0.f,0.f,0.f,0.f};
        f32x4 a4 = {0.f,0.f,0.f,0.f};
        int p = q;
        for (; p + 4 < deg; p += 8) {
            int s0 = ssrc[wid][p];
            int s1 = ssrc[wid][p + 4];
            const bf16* hp0 = hlin + (size_t)s0 * 320;
            const bf16* hp1 = hlin + (size_t)s1 * 320;
            bf16x8 u0 = *(const bf16x8*)(hp0 + f0);
            bf16x8 u1 = *(const bf16x8*)(hp0 + f0 + 8);
            bf16x4 u2 = *(const bf16x4*)(hp0 + f1);
            bf16x8 v0 = *(const bf16x8*)(hp1 + f0);
            bf16x8 v1 = *(const bf16x8*)(hp1 + f0 + 8);
            bf16x4 v2 = *(const bf16x4*)(hp1 + f1);
            float w00 = el[wid][p * 10 + (g >> 1)];
            float w02 = el[wid][p * 10 + 8 + (g >> 3)];
            float w10 = el[wid][(p + 4) * 10 + (g >> 1)];
            float w12 = el[wid][(p + 4) * 10 + 8 + (g >> 3)];
#pragma unroll
            for (int k = 0; k < 4; ++k) {
                a0[k] += w00 * bf2fs(u0[k]);
                a1[k] += w00 * bf2fs(u0[4 + k]);
                a2[k] += w00 * bf2fs(u1[k]);
                a3[k] += w00 * bf2fs(u1[4 + k]);
                a4[k] += w02 * bf2fs(u2[k]);
                a0[k] += w10 * bf2fs(v0[k]);
                a1[k] += w10 * bf2fs(v0[4 + k]);
                a2[k] += w10 * bf2fs(v1[k]);
                a3[k] += w10 * bf2fs(v1[4 + k]);
                a4[k] += w12 * bf2fs(v2[k]);
            }
        }
        if (p < deg) {
            int s0 = ssrc[wid][p];
            const bf16* hp0 = hlin + (size_t)s0 * 320;
            bf16x8 u0 = *(const bf16x8*)(hp0 + f0);
            bf16x8 u1 = *(const bf16x8*)(hp0 + f0 + 8);
            bf16x4 u2 = *(const bf16x4*)(hp0 + f1);
            float w00 = el[wid][p * 10 + (g >> 1)];
            float w02 = el[wid][p * 10 + 8 + (g >> 3)];
#pragma unroll
            for (int k = 0; k < 4; ++k) {
                a0[k] += w00 * bf2fs(u0[k]);
                a1[k] += w00 * bf2fs(u0[4 + k]);
                a2[k] += w00 * bf2fs(u1[k]);
                a3[k] += w00 * bf2fs(u1[4 + k]);
                a4[k] += w02 * bf2fs(u2[k]);
            }
        }
#pragma unroll
        for (int k = 0; k < 4; ++k) {
            a0[k] += __shfl_xor(a0[k], 16); a1[k] += __shfl_xor(a1[k], 16);
            a2[k] += __shfl_xor(a2[k], 16); a3[k] += __shfl_xor(a3[k], 16);
            a4[k] += __shfl_xor(a4[k], 16);
            a0[k] += __shfl_xor(a0[k], 32); a1[k] += __shfl_xor(a1[k], 32);
            a2[k] += __shfl_xor(a2[k], 32); a3[k] += __shfl_xor(a3[k], 32);
            a4[k] += __shfl_xor(a4[k], 32);
        }
        float* scratch = &el[wid][0];
        if (lane < 16) {
            float inv0 = idn[wid][g >> 1];
            float inv2 = idn[wid][8 + (g >> 3)];
#pragma unroll
            for (int k = 0; k < 4; ++k) {
                scratch[f0 + k]      = a0[k] * inv0;
                scratch[f0 + 4 + k]  = a1[k] * inv0;
                scratch[f0 + 8 + k]  = a2[k] * inv0;
                scratch[f0 + 12 + k] = a3[k] * inv0;
                scratch[f1 + k]      = a4[k] * inv2;
            }
        }
        if (lane < 32) {
            float s = 0.f;
#pragma unroll
            for (int h = 0; h < 10; ++h) s += scratch[h * 32 + lane];
            float v = s * 0.1f + loadf(bias, lane, isf32)
                    + bf2f(identb[(size_t)d * 32 + lane]);
            if (isf32) ((float*)out)[(size_t)d * 32 + lane] = v;
            else ((bf16*)out)[(size_t)d * 32 + lane] = __float2bfloat16(v);
        }
        return;
    }

    // ---- slow path (deg > CAP): recompute logits per lane-channel-group ----
    f32x4 acc[2] = {(f32x4){0.f,0.f,0.f,0.f}, (f32x4){0.f,0.f,0.f,0.f}};
    for (int j = 0; j < nj; ++j) {
        int f0 = (lane + 64 * j) * 4;
        if (f0 >= F) continue;
        int hj = f0 >> 5;
        float ad = adst[(size_t)d * H + hj];
        float m = -1e30f;
        for (int p = 0; p < deg; ++p) {
            int e = csr_e[lo + p];
            int s = (e < E) ? esrc[e] : (e - E);
            float v = asrc[(size_t)s * H + hj] + ad;
            v = (v > 0.f) ? v : 0.2f * v;
            m = fmaxf(m, v);
        }
        float den = 0.f;
        f32x4 a4 = {0.f, 0.f, 0.f, 0.f};
        for (int p = 0; p < deg; ++p) {
            int e = csr_e[lo + p];
            int s = (e < E) ? esrc[e] : (e - E);
            float v = asrc[(size_t)s * H + hj] + ad;
            v = (v > 0.f) ? v : 0.2f * v;
            float t = __expf(v - m);
            den += t;
            bf16x4 hv = *(const bf16x4*)(hlin + (size_t)s * F + f0);
            for (int k = 0; k < 4; ++k) a4[k] += t * bf2fs(hv[k]);
        }
        float inv = 1.f / (den + 1e-16f);
        for (int k = 0; k < 4; ++k) acc[j][k] = a4[k] * inv;
    }
    if (mode == 1) {
        int f0 = lane * 4;
        bf16x4 ob;
#pragma unroll
        for (int k = 0; k < 4; ++k) {
            float v = acc[0][k] + loadf(bias, f0 + k, isf32);
            v = (v > 0.f) ? v : (__expf(v) - 1.f);
            v += bf2f(identb[(size_t)d * F + f0 + k]);
            ob[k] = f2bfs(v);
        }
        *(bf16x4*)(outb + (size_t)d * F + f0) = ob;
    } else {
        float* scratch = &el[wid][0];
#pragma unroll
        for (int j = 0; j < 2; ++j) {
            int f0 = (lane + 64 * j) * 4;
            if (j < nj && f0 < F) {
#pragma unroll
                for (int k = 0; k < 4; ++k) scratch[f0 + k] = acc[j][k];
            }
        }
        if (lane < 32) {
            float s = 0.f;
            for (int h = 0; h < H; ++h) s += scratch[h * 32 + lane];
            float v = s * (1.f / (float)H) + loadf(bias, lane, isf32)
                    + bf2f(identb[(size_t)d * 32 + lane]);
            if (isf32) ((float*)out)[(size_t)d * 32 + lane] = v;
            else ((bf16*)out)[(size_t)d * 32 + lane] = __float2bfloat16(v);
        }
    }
}

extern "C" void kernel_launch(void* const* d_in, const int* in_sizes, int n_in,
                              void* d_out, int out_size, void* d_ws, size_t ws_size,
                              hipStream_t stream) {
    const int IN = 256, C = 32;
    const int N = in_sizes[0] / IN;
    const int E = in_sizes[1] / 2;
    const int ET = E + N;

    const void* x    = d_in[0];
    const int*  edge = (const int*)d_in[1];
    const void* W1 = d_in[2];
    const void* a1s = d_in[3];
    const void* a1d = d_in[4];
    const void* b1 = d_in[5];
    const void* W2 = d_in[6];
    const void* a2s = d_in[7];
    const void* a2d = d_in[8];
    const void* b2 = d_in[9];
    const void* W3 = d_in[10];
    const void* a3s = d_in[11];
    const void* a3d = d_in[12];
    const void* b3 = d_in[13];
    const void* P1W = d_in[14];
    const void* P1b = d_in[15];
    const void* P3W = d_in[16];
    const void* P3b = d_in[17];

    char* ws = (char*)d_ws;
    size_t off = 0;
    auto alloc = [&](size_t bytes) -> void* {
        void* p = ws + off;
        off = (off + bytes + 255) & ~(size_t)255;
        return p;
    };
    bf16* fxb   = (bf16*)alloc((size_t)N * 256 * 2);    // bf16 input
    bf16* fyb   = (bf16*)alloc((size_t)N * 256 * 2);    // bf16 layer outputs
    bf16* fhb   = (bf16*)alloc((size_t)N * 320 * 2);    // h_lin bf16 (per layer)
    bf16* fidb  = (bf16*)alloc((size_t)N * 256 * 2);    // identity1 / identity3 (bf16)
    float* fasrc = (float*)alloc((size_t)N * 10 * 4);
    float* fadst = (float*)alloc((size_t)N * 10 * 4);
    bf16* wc1   = (bf16*)alloc((size_t)512 * 256 * 2);  // [W1; P1W]
    bf16* wb2   = (bf16*)alloc((size_t)256 * 256 * 2);
    bf16* wc3   = (bf16*)alloc((size_t)384 * 256 * 2);  // [W3; P3W; 32 pad rows]
    int*  isrc  = (int*)alloc((size_t)E * 4);
    int*  idst  = (int*)alloc((size_t)E * 4);
    int*  irow  = (int*)alloc((size_t)(N + 1) * 4);
    int*  icur  = (int*)alloc((size_t)N * 4);
    int*  icsr  = (int*)alloc((size_t)ET * 4);
    int*  flags = (int*)alloc(4 * 4);
    (void)ws_size;

    auto cdiv = [](int a, int b) { return (a + b - 1) / b; };

    // zero flags + degree counters
    k_zero<<<cdiv(N, 256), 256, 0, stream>>>(flags, icur, N);

    // dtype detection (tiny prefix probe, spread over ~24 blocks)
    int nprobe_x = (N * 256 < 16384) ? N * 256 : 16384;
    int nprobe_e = (2 * E < 8192) ? 2 * E : 8192;
    int bx = cdiv(nprobe_x, 256) < 16 ? cdiv(nprobe_x, 256) : 16;
    int be = cdiv(nprobe_e, 256) < 8 ? cdiv(nprobe_e, 256) : 8;
    k_detect<<<bx + be, 256, 0, stream>>>(
        (const unsigned short*)x, edge, flags, nprobe_x, nprobe_e, bx);

    // casts + edge normalize + degree count in one launch
    int c_x = N * 256 / 8, c_w = 256 * 256 / 8, c_w3 = 320 * 256 / 8, c_p3 = 32 * 256 / 8;
    int ctot = c_x + 3 * c_w + c_w3 + c_p3;
    int cb = cdiv(ctot, 256);
    k_cast_norm<<<cb + cdiv(E, 256), 256, 0, stream>>>(
        x, fxb, c_x,
        W1, wc1, c_w,
        P1W, wc1 + (size_t)256 * 256, c_w,
        W2, wb2, c_w,
        W3, wc3, c_w3,
        P3W, wc3 + (size_t)320 * 256, c_p3,
        edge, isrc, idst, icur, E, flags, cb);

    k_scan<<<1, 1024, 0, stream>>>(icur, irow, N);
    k_fill<<<cdiv(ET, 256), 256, 0, stream>>>(idst, icur, irow, icsr, E, N);

    int gx = cdiv(N, 64);
    int ga = cdiv(N, 4);

    // ---- Layer 1: H=8; combined [W1;P1W] GEMM + fused alpha ----
    {
        int H = 8;
        k_gemm_split<4><<<dim3(gx, 8), 256, 0, stream>>>(
            fxb, wc1, P1b, flags, fhb, 256, 256, fidb, 256, 256, N, 512, 256,
            a1s, a1d, fasrc, fadst, H);
        k_fused_agg<<<ga, 256, 0, stream>>>(fhb, fasrc, fadst, isrc, irow, icsr,
                                            b1, fidb, nullptr, fyb, flags, E, N, H, 1);
    }
    // ---- Layer 2: H=8, identity = layer-1 output (bf16, in-place) ----
    {
        int H = 8;
        k_gemm_split<4><<<dim3(gx, 4), 256, 0, stream>>>(
            fyb, wb2, nullptr, flags, fhb, 256, 256, nullptr, 0, 0, N, 256, 256,
            a2s, a2d, fasrc, fadst, H);
        k_fused_agg<<<ga, 256, 0, stream>>>(fhb, fasrc, fadst, isrc, irow, icsr,
                                            b2, fyb, nullptr, fyb, flags, E, N, H, 1);
    }
    // ---- Layer 3: H=10, concat=False; combined [W3;P3W;pad] GEMM ----
    {
        int H = 10;
        k_gemm_split<4><<<dim3(gx, 6), 256, 0, stream>>>(
            fyb, wc3, P3b, flags, fhb, 320, 320, fidb, 32, 32, N, 384, 256,
            a3s, a3d, fasrc, fadst, H);
        k_fused_agg<<<ga, 256, 0, stream>>>(fhb, fasrc, fadst, isrc, irow, icsr,
                                            b3, fidb, d_out, nullptr, flags, E, N, H, 2);
    }
}

// Round 13
// 199.031 us; speedup vs baseline: 1.1086x; 1.0133x over previous
//
#include <hip/hip_runtime.h>
#include <hip/hip_bf16.h>

typedef __hip_bfloat16 bf16;
typedef __attribute__((ext_vector_type(8))) short bf16x8;
typedef __attribute__((ext_vector_type(4))) short bf16x4;
typedef __attribute__((ext_vector_type(4))) float f32x4;

// ---------------------------------------------------------------------------
// 3-layer GAT forward. Dtype-adaptive (observed world: floats=bf16, edges=i32).
// flags[0]=1 if NaN/Inf ushort pattern in x-prefix (=> x is f32)
// flags[1]=1 if any odd 32-bit word of edge prefix nonzero (=> edges i32)
// flags[2]=1 if any even-index ushort of x-prefix nonzero
// isf32 = flags[0] || !flags[2]
// r11 lesson: detection must be MULTI-block (single block = 40us latency chain).
// r12 lesson: per-launch gap ~1us; optimize inside kernels, not launch count.
// ---------------------------------------------------------------------------

static __device__ __forceinline__ float bf2f(bf16 v) { return __bfloat162float(v); }
static __device__ __forceinline__ float bf2fs(short v) {
    unsigned int u = ((unsigned int)(unsigned short)v) << 16;
    return __builtin_bit_cast(float, u);
}
static __device__ __forceinline__ short f2bfs(float f) {
    bf16 b = __float2bfloat16(f);
    return __builtin_bit_cast(short, b);
}
static __device__ __forceinline__ float loadf(const void* p, size_t i, int isf32) {
    return isf32 ? ((const float*)p)[i] : bf2f(((const bf16*)p)[i]);
}
static __device__ __forceinline__ int get_isf32(const int* flags) {
    return (flags[0] | (flags[2] == 0)) ? 1 : 0;
}
// same-wave LDS ordering fence (el/ssrc/idn are per-wave private; no block barrier
// needed — this only drains LDS ops and stops compiler reordering of memory ops)
static __device__ __forceinline__ void wave_lds_fence() {
    asm volatile("s_waitcnt lgkmcnt(0)" ::: "memory");
}

// zero flags[4] + cnt[N]
__global__ void k_zero(int* __restrict__ flags, int* __restrict__ cnt, int N) {
    int i = blockIdx.x * blockDim.x + threadIdx.x;
    if (i < 4) flags[i] = 0;
    for (; i < N; i += gridDim.x * blockDim.x) cnt[i] = 0;
}

// detection: tiny probe spread over many blocks, LDS aggregation, <=3 atomics/blk
__global__ void k_detect(const unsigned short* __restrict__ xu, const int* __restrict__ ew,
                         int* __restrict__ flags, int nx, int ne2, int bx) {
    __shared__ int lf[3];
    if (threadIdx.x < 3) lf[threadIdx.x] = 0;
    __syncthreads();
    if ((int)blockIdx.x < bx) {
        for (int i = blockIdx.x * 256 + threadIdx.x; i < nx; i += bx * 256) {
            unsigned short v = xu[i];
            if ((v & 0x7F80u) == 0x7F80u) lf[0] = 1;
            if (((i & 1) == 0) && v != 0) lf[2] = 1;
        }
    } else {
        int nb = gridDim.x - bx;
        for (int i = (blockIdx.x - bx) * 256 + threadIdx.x; i < ne2; i += nb * 256) {
            if ((i & 1) && ew[i] != 0) lf[1] = 1;
        }
    }
    __syncthreads();
    if (threadIdx.x == 0) {
        if (lf[0]) atomicOr(&flags[0], 1);
        if (lf[1]) atomicOr(&flags[1], 1);
        if (lf[2]) atomicOr(&flags[2], 1);
    }
}

// 8-elem vectorized adaptive cast
static __device__ __forceinline__ void cast8(const void* src, bf16* dst, int i8, int isf32) {
    if (isf32) {
        f32x4 a = ((const f32x4*)src)[2 * i8];
        f32x4 b = ((const f32x4*)src)[2 * i8 + 1];
        bf16x8 o;
        o[0] = f2bfs(a[0]); o[1] = f2bfs(a[1]); o[2] = f2bfs(a[2]); o[3] = f2bfs(a[3]);
        o[4] = f2bfs(b[0]); o[5] = f2bfs(b[1]); o[6] = f2bfs(b[2]); o[7] = f2bfs(b[3]);
        ((bf16x8*)dst)[i8] = o;
    } else {
        ((bf16x8*)dst)[i8] = ((const bf16x8*)src)[i8];
    }
}

// blocks [0, cb): input casts (s0 = x, skipped in bf16 world: GEMM reads x directly)
// blocks [cb, ...): edge normalize + degree count.
__global__ void k_cast_norm(const void* s0, bf16* d0, int c0,
                            const void* s1, bf16* d1, int c1,
                            const void* s2, bf16* d2, int c2,
                            const void* s3, bf16* d3, int c3,
                            const void* s4, bf16* d4, int c4,
                            const void* s5, bf16* d5, int c5,
                            const int* __restrict__ w, int* __restrict__ es,
                            int* __restrict__ ed, int* __restrict__ cnt, int E,
                            const int* __restrict__ flags, int cb) {
    if ((int)blockIdx.x < cb) {
        int t = blockIdx.x * 256 + threadIdx.x;
        int isf32 = get_isf32(flags);
        if (t < c0) { if (isf32) cast8(s0, d0, t, 1); return; } t -= c0;
        if (t < c1) { cast8(s1, d1, t, isf32); return; } t -= c1;
        if (t < c2) { cast8(s2, d2, t, isf32); return; } t -= c2;
        if (t < c3) { cast8(s3, d3, t, isf32); return; } t -= c3;
        if (t < c4) { cast8(s4, d4, t, isf32); return; } t -= c4;
        if (t < c5) { cast8(s5, d5, t, isf32); }
    } else {
        int e = (blockIdx.x - cb) * 256 + threadIdx.x;
        if (e >= E) return;
        int sv, dv;
        if (flags[1] == 0) {  // int64
            sv = w[2 * (size_t)e];
            dv = w[2 * (size_t)E + 2 * (size_t)e];
        } else {              // int32
            sv = w[e];
            dv = w[(size_t)E + e];
        }
        es[e] = sv;
        ed[e] = dv;
        atomicAdd(&cnt[dv], 1);
    }
}

// single-block vertical scan: thread-strips + one 1024-wide LDS scan.
__global__ void k_scan(int* __restrict__ cnt, int* __restrict__ row_ptr, int N) {
    __shared__ int part[1024];
    int tid = threadIdx.x;
    int vpt = (N + 1023) >> 10;
    int i0 = tid * vpt;
    int i1 = i0 + vpt; if (i1 > N) i1 = N;
    int s = 0;
    for (int i = i0; i < i1; ++i) s += cnt[i] + 1;
    part[tid] = s;
    __syncthreads();
    for (int off = 1; off < 1024; off <<= 1) {
        int t = (tid >= off) ? part[tid - off] : 0;
        __syncthreads();
        part[tid] += t;
        __syncthreads();
    }
    int run = (tid == 0) ? 0 : part[tid - 1];
    for (int i = i0; i < i1; ++i) {
        int c = cnt[i] + 1;
        cnt[i] = run;            // cursor = exclusive prefix
        run += c;
        row_ptr[i + 1] = run;
    }
    if (tid == 0) row_ptr[0] = 0;
}

// fill CSR: edges via atomic cursor; self-loop of node d at row_ptr[d+1]-1.
__global__ void k_fill(const int* __restrict__ edst, int* __restrict__ cursor,
                       const int* __restrict__ row_ptr, int* __restrict__ csr_e,
                       int E, int N) {
    int e = blockIdx.x * blockDim.x + threadIdx.x;
    if (e < E) {
        int d = edst[e];
        int pos = atomicAdd(&cursor[d], 1);
        csr_e[pos] = e;
    } else if (e < E + N) {
        int d = e - E;
        csr_e[row_ptr[d + 1] - 1] = e;
    }
}

// ---------------------------------------------------------------------------
// Unified MFMA GEMM, split output (both bf16) + fused attention-logit epilogue.
// KK is compile-time K (=256) -> fully unrolled K-loop, loads hoisted early.
// Araw: optional raw input pointer; in bf16 world A := Araw (zero-copy of x).
// ---------------------------------------------------------------------------
template<int NT, int KK>
__global__ void k_gemm_split(const bf16* __restrict__ Acast, const void* __restrict__ Araw,
                             const bf16* __restrict__ W,
                             const void* __restrict__ bias1, const int* __restrict__ flags,
                             bf16* __restrict__ out0, int S0, int ld0,
                             bf16* __restrict__ out1, int ld1, int n1,
                             int M, int Fo,
                             const void* __restrict__ aS, const void* __restrict__ aD,
                             float* __restrict__ asrc, float* __restrict__ adst, int H) {
    int wid = threadIdx.x >> 6;
    int lane = threadIdx.x & 63;
    int mrow = blockIdx.x * 64 + wid * 16;
    if (mrow >= M) return;
    int isf32 = get_isf32(flags);
    const bf16* A = (Araw && !isf32) ? (const bf16*)Araw : Acast;
    int ncol = blockIdx.y * (NT * 16);
    int r = lane & 15, g = lane >> 4;

    f32x4 acc[NT];
#pragma unroll
    for (int t = 0; t < NT; ++t) acc[t] = (f32x4){0.f, 0.f, 0.f, 0.f};

    const bf16* arow = A + (size_t)(mrow + r) * KK + g * 8;
    const bf16* wbase = W + (size_t)(ncol + r) * KK + g * 8;
#pragma unroll
    for (int k0 = 0; k0 < KK; k0 += 32) {
        bf16x8 af = *(const bf16x8*)(arow + k0);
#pragma unroll
        for (int t = 0; t < NT; ++t) {
            bf16x8 bfr = *(const bf16x8*)(wbase + (size_t)t * 16 * KK + k0);
            acc[t] = __builtin_amdgcn_mfma_f32_16x16x32_bf16(af, bfr, acc[t], 0, 0, 0);
        }
    }

    // main C write
#pragma unroll
    for (int t = 0; t < NT; ++t) {
        int n = ncol + t * 16 + r;
        bool is0 = n < S0;
        int jc = n - S0;
        float bv = (!is0 && jc < n1 && bias1) ? loadf(bias1, jc, isf32) : 0.f;
#pragma unroll
        for (int j = 0; j < 4; ++j) {
            int m = mrow + 4 * g + j;
            float v = acc[t][j] + bv;
            if (is0) out0[(size_t)m * ld0 + n] = __float2bfloat16(v);
            else if (jc < n1) out1[(size_t)m * ld1 + jc] = __float2bfloat16(v);
        }
    }

    // fused alpha epilogue (NT==4 blocks fully inside [0,S0): 2 whole heads)
    if (aS && ncol < S0) {
        float ps[2][4], pd[2][4];
#pragma unroll
        for (int hb = 0; hb < 2; ++hb)
#pragma unroll
            for (int j = 0; j < 4; ++j) { ps[hb][j] = 0.f; pd[hb][j] = 0.f; }
#pragma unroll
        for (int t = 0; t < NT; ++t) {
            int col = ncol + t * 16 + r;
            float asv = loadf(aS, col, isf32);
            float adv = loadf(aD, col, isf32);
#pragma unroll
            for (int j = 0; j < 4; ++j) {
                ps[t >> 1][j] += acc[t][j] * asv;
                pd[t >> 1][j] += acc[t][j] * adv;
            }
        }
#pragma unroll
        for (int mk = 1; mk <= 8; mk <<= 1) {
#pragma unroll
            for (int hb = 0; hb < 2; ++hb)
#pragma unroll
                for (int j = 0; j < 4; ++j) {
                    ps[hb][j] += __shfl_xor(ps[hb][j], mk);
                    pd[hb][j] += __shfl_xor(pd[hb][j], mk);
                }
        }
        if (r == 0) {
            int hA = ncol >> 5, hB = hA + 1;
#pragma unroll
            for (int j = 0; j < 4; ++j) {
                int m = mrow + 4 * g + j;
                asrc[(size_t)m * H + hA] = ps[0][j];
                asrc[(size_t)m * H + hB] = ps[1][j];
                adst[(size_t)m * H + hA] = pd[0][j];
                adst[(size_t)m * H + hB] = pd[1][j];
            }
        }
    }
}

// ---------------------------------------------------------------------------
// Fused per-dst-node softmax + aggregation. One wave per dst node, 4 waves/blk.
// el/ssrc/idn are PER-WAVE private => no __syncthreads; same-wave LDS ordering
// via wave_lds_fence() (lgkmcnt drain + compiler memory fence). Waves are
// fully decoupled (no slowest-degree coupling).
// Gathers: 4-edge-parallel (16 lanes/edge), unroll-2 over edge stride.
// Degree > CAP: slow recompute path.
// ---------------------------------------------------------------------------
#define CAP 96
__global__ void k_fused_agg(const bf16* __restrict__ hlin,
                            const float* __restrict__ asrc, const float* __restrict__ adst,
                            const int* __restrict__ esrc, const int* __restrict__ row_ptr,
                            const int* __restrict__ csr_e,
                            const void* __restrict__ bias, const bf16* __restrict__ identb,
                            void* __restrict__ out, bf16* __restrict__ outb,
                            const int* __restrict__ flags,
                            int E, int N, int H, int mode) {
    __shared__ float el[4][CAP * 10];   // logits -> exp weights; scratch in mode 2
    __shared__ int   ssrc[4][CAP];
    __shared__ float idn[4][10];
    int wid = threadIdx.x >> 6, lane = threadIdx.x & 63;
    int d = blockIdx.x * 4 + wid;
    bool active = d < N;
    int isf32 = get_isf32(flags);
    int F = H * 32;
    int nj = (F + 255) >> 8;
    int lo = 0, deg = 0;
    if (active) { lo = row_ptr[d]; deg = row_ptr[d + 1] - lo; }
    bool fast = deg <= CAP;
    if (!active) return;

    // ---- Pass A: logits into LDS (per-wave region) ----
    if (fast) {
        int EC = 64 / H;
        int h = lane % H, ei = lane / H;
        float ad = adst[(size_t)d * H + h];
        for (int base = 0; base < deg; base += EC) {
            int p = base + ei;
            if (ei < EC && p < deg) {
                int e = csr_e[lo + p];
                int s = (e < E) ? esrc[e] : (e - E);
                float v = asrc[(size_t)s * H + h] + ad;
                v = (v > 0.f) ? v : 0.2f * v;
                el[wid][p * H + h] = v;
                if (h == 0) ssrc[wid][p] = s;
            }
        }
    }
    wave_lds_fence();
    // ---- Pass M: per-head softmax normalization ----
    if (fast) {
        if (H == 8) {
            int h = lane & 7, sub = lane >> 3;
            float m = -1e30f;
            for (int p = sub; p < deg; p += 8) m = fmaxf(m, el[wid][p * 8 + h]);
            m = fmaxf(m, __shfl_xor(m, 8));
            m = fmaxf(m, __shfl_xor(m, 16));
            m = fmaxf(m, __shfl_xor(m, 32));
            float den = 0.f;
            for (int p = sub; p < deg; p += 8) {
                float t = __expf(el[wid][p * 8 + h] - m);
                el[wid][p * 8 + h] = t;
                den += t;
            }
            den += __shfl_xor(den, 8);
            den += __shfl_xor(den, 16);
            den += __shfl_xor(den, 32);
            if (lane < 8) idn[wid][lane] = 1.f / (den + 1e-16f);
        } else if (lane < H) {
            float m = -1e30f;
            for (int p = 0; p < deg; ++p) m = fmaxf(m, el[wid][p * H + lane]);
            float den = 0.f;
            for (int p = 0; p < deg; ++p) {
                float t = __expf(el[wid][p * H + lane] - m);
                el[wid][p * H + lane] = t;
                den += t;
            }
            idn[wid][lane] = 1.f / (den + 1e-16f);
        }
    }
    wave_lds_fence();

    if (mode == 1 && fast) {
        // ---- F=256, H=8: 4-edge-parallel, unroll-2 (edges p, p+4) ----
        int g = lane & 15, q = lane >> 4;
        int f0 = g * 16;
        f32x4 a0 = {0.f,0.f,0.f,0.f}, a1 = {0.f,0.f,0.f,0.f};
        f32x4 a2 = {0.f,0.f,0.f,0.f}, a3 = {0.f,0.f,0.f,0.f};
        int p = q;
        for (; p + 4 < deg; p += 8) {
            int s0 = ssrc[wid][p];
            int s1 = ssrc[wid][p + 4];
            const bf16* hp0 = hlin + (size_t)s0 * 256 + f0;
            const bf16* hp1 = hlin + (size_t)s1 * 256 + f0;
            bf16x8 u0 = *(const bf16x8*)hp0;
            bf16x8 u1 = *(const bf16x8*)(hp0 + 8);
            bf16x8 v0 = *(const bf16x8*)hp1;
            bf16x8 v1 = *(const bf16x8*)(hp1 + 8);
            float w0 = el[wid][p * 8 + (g >> 1)];
            float w1 = el[wid][(p + 4) * 8 + (g >> 1)];
#pragma unroll
            for (int k = 0; k < 4; ++k) {
                a0[k] += w0 * bf2fs(u0[k]);
                a1[k] += w0 * bf2fs(u0[4 + k]);
                a2[k] += w0 * bf2fs(u1[k]);
                a3[k] += w0 * bf2fs(u1[4 + k]);
                a0[k] += w1 * bf2fs(v0[k]);
                a1[k] += w1 * bf2fs(v0[4 + k]);
                a2[k] += w1 * bf2fs(v1[k]);
                a3[k] += w1 * bf2fs(v1[4 + k]);
            }
        }
        if (p < deg) {
            int s0 = ssrc[wid][p];
            const bf16* hp0 = hlin + (size_t)s0 * 256 + f0;
            bf16x8 u0 = *(const bf16x8*)hp0;
            bf16x8 u1 = *(const bf16x8*)(hp0 + 8);
            float w0 = el[wid][p * 8 + (g >> 1)];
#pragma unroll
            for (int k = 0; k < 4; ++k) {
                a0[k] += w0 * bf2fs(u0[k]);
                a1[k] += w0 * bf2fs(u0[4 + k]);
                a2[k] += w0 * bf2fs(u1[k]);
                a3[k] += w0 * bf2fs(u1[4 + k]);
            }
        }
#pragma unroll
        for (int k = 0; k < 4; ++k) {
            a0[k] += __shfl_xor(a0[k], 16); a1[k] += __shfl_xor(a1[k], 16);
            a2[k] += __shfl_xor(a2[k], 16); a3[k] += __shfl_xor(a3[k], 16);
            a0[k] += __shfl_xor(a0[k], 32); a1[k] += __shfl_xor(a1[k], 32);
            a2[k] += __shfl_xor(a2[k], 32); a3[k] += __shfl_xor(a3[k], 32);
        }
        if (lane < 16) {
            float inv = idn[wid][g >> 1];
            const bf16* idp = identb + (size_t)d * 256 + f0;
            bf16x8 id0 = *(const bf16x8*)idp;
            bf16x8 id1 = *(const bf16x8*)(idp + 8);
            bf16* ob = outb + (size_t)d * 256 + f0;
            f32x4 av[4] = {a0, a1, a2, a3};
            bf16x8 obv0, obv1;
#pragma unroll
            for (int i = 0; i < 4; ++i) {
#pragma unroll
                for (int k = 0; k < 4; ++k) {
                    float v = av[i][k] * inv + loadf(bias, f0 + 4 * i + k, isf32);
                    v = (v > 0.f) ? v : (__expf(v) - 1.f);  // ELU
                    int e8 = 4 * i + k;
                    v += bf2fs((e8 < 8) ? id0[e8] : id1[e8 - 8]);
                    if (i < 2) obv0[e8] = f2bfs(v);
                    else       obv1[e8 - 8] = f2bfs(v);
                }
            }
            *(bf16x8*)ob = obv0;
            *(bf16x8*)(ob + 8) = obv1;
        }
        return;
    }

    if (mode == 2 && fast) {
        // ---- F=320, H=10: 4-edge-parallel, unroll-2 ----
        int g = lane & 15, q = lane >> 4;
        int f0 = g * 16;
        int f1 = 256 + g * 4;
        f32x4 a0 = {0.f,0.f,0.f,0.f}, a1 = {0.f,0.f,0.f,0.f};
        f32x4 a2 = {0.f,0.f,0.f,0.f}, a3 = {0.f,0.f,0.f,0.f};
        f32x4 a4 = {0.f,0.f,0.f,0.f};
        int p = q;
        for (; p + 4 < deg; p += 8) {
            int s0 = ssrc[wid][p];
            int s1 = ssrc[wid][p + 4];
            const bf16* hp0 = hlin + (size_t)s0 * 320;
            const bf16* hp1 = hlin + (size_t)s1 * 320;
            bf16x8 u0 = *(const bf16x8*)(hp0 + f0);
            bf16x8 u1 = *(const bf16x8*)(hp0 + f0 + 8);
            bf16x4 u2 = *(const bf16x4*)(hp0 + f1);
            bf16x8 v0 = *(const bf16x8*)(hp1 + f0);
            bf16x8 v1 = *(const bf16x8*)(hp1 + f0 + 8);
            bf16x4 v2 = *(const bf16x4*)(hp1 + f1);
            float w00 = el[wid][p * 10 + (g >> 1)];
            float w02 = el[wid][p * 10 + 8 + (g >> 3)];
            float w10 = el[wid][(p + 4) * 10 + (g >> 1)];
            float w12 = el[wid][(p + 4) * 10 + 8 + (g >> 3)];
#pragma unroll
            for (int k = 0; k < 4; ++k) {
                a0[k] += w00 * bf2fs(u0[k]);
                a1[k] += w00 * bf2fs(u0[4 + k]);
                a2[k] += w00 * bf2fs(u1[k]);
                a3[k] += w00 * bf2fs(u1[4 + k]);
                a4[k] += w02 * bf2fs(u2[k]);
                a0[k] += w10 * bf2fs(v0[k]);
                a1[k] += w10 * bf2fs(v0[4 + k]);
                a2[k] += w10 * bf2fs(v1[k]);
                a3[k] += w10 * bf2fs(v1[4 + k]);
                a4[k] += w12 * bf2fs(v2[k]);
            }
        }
        if (p < deg) {
            int s0 = ssrc[wid][p];
            const bf16* hp0 = hlin + (size_t)s0 * 320;
            bf16x8 u0 = *(const bf16x8*)(hp0 + f0);
            bf16x8 u1 = *(const bf16x8*)(hp0 + f0 + 8);
            bf16x4 u2 = *(const bf16x4*)(hp0 + f1);
            float w00 = el[wid][p * 10 + (g >> 1)];
            float w02 = el[wid][p * 10 + 8 + (g >> 3)];
#pragma unroll
            for (int k = 0; k < 4; ++k) {
                a0[k] += w00 * bf2fs(u0[k]);
                a1[k] += w00 * bf2fs(u0[4 + k]);
                a2[k] += w00 * bf2fs(u1[k]);
                a3[k] += w00 * bf2fs(u1[4 + k]);
                a4[k] += w02 * bf2fs(u2[k]);
            }
        }
#pragma unroll
        for (int k = 0; k < 4; ++k) {
            a0[k] += __shfl_xor(a0[k], 16); a1[k] += __shfl_xor(a1[k], 16);
            a2[k] += __shfl_xor(a2[k], 16); a3[k] += __shfl_xor(a3[k], 16);
            a4[k] += __shfl_xor(a4[k], 16);
            a0[k] += __shfl_xor(a0[k], 32); a1[k] += __shfl_xor(a1[k], 32);
            a2[k] += __shfl_xor(a2[k], 32); a3[k] += __shfl_xor(a3[k], 32);
            a4[k] += __shfl_xor(a4[k], 32);
        }
        float* scratch = &el[wid][0];
        if (lane < 16) {
            float inv0 = idn[wid][g >> 1];
            float inv2 = idn[wid][8 + (g >> 3)];
#pragma unroll
            for (int k = 0; k < 4; ++k) {
                scratch[f0 + k]      = a0[k] * inv0;
                scratch[f0 + 4 + k]  = a1[k] * inv0;
                scratch[f0 + 8 + k]  = a2[k] * inv0;
                scratch[f0 + 12 + k] = a3[k] * inv0;
                scratch[f1 + k]      = a4[k] * inv2;
            }
        }
        wave_lds_fence();
        if (lane < 32) {
            float s = 0.f;
#pragma unroll
            for (int h = 0; h < 10; ++h) s += scratch[h * 32 + lane];
            float v = s * 0.1f + loadf(bias, lane, isf32)
                    + bf2f(identb[(size_t)d * 32 + lane]);
            if (isf32) ((float*)out)[(size_t)d * 32 + lane] = v;
            else ((bf16*)out)[(size_t)d * 32 + lane] = __float2bfloat16(v);
        }
        return;
    }

    // ---- slow path (deg > CAP): recompute logits per lane-channel-group ----
    f32x4 acc[2] = {(f32x4){0.f,0.f,0.f,0.f}, (f32x4){0.f,0.f,0.f,0.f}};
    for (int j = 0; j < nj; ++j) {
        int f0 = (lane + 64 * j) * 4;
        if (f0 >= F) continue;
        int hj = f0 >> 5;
        float ad = adst[(size_t)d * H + hj];
        float m = -1e30f;
        for (int p = 0; p < deg; ++p) {
            int e = csr_e[lo + p];
            int s = (e < E) ? esrc[e] : (e - E);
            float v = asrc[(size_t)s * H + hj] + ad;
            v = (v > 0.f) ? v : 0.2f * v;
            m = fmaxf(m, v);
        }
        float den = 0.f;
        f32x4 a4 = {0.f, 0.f, 0.f, 0.f};
        for (int p = 0; p < deg; ++p) {
            int e = csr_e[lo + p];
            int s = (e < E) ? esrc[e] : (e - E);
            float v = asrc[(size_t)s * H + hj] + ad;
            v = (v > 0.f) ? v : 0.2f * v;
            float t = __expf(v - m);
            den += t;
            bf16x4 hv = *(const bf16x4*)(hlin + (size_t)s * F + f0);
            for (int k = 0; k < 4; ++k) a4[k] += t * bf2fs(hv[k]);
        }
        float inv = 1.f / (den + 1e-16f);
        for (int k = 0; k < 4; ++k) acc[j][k] = a4[k] * inv;
    }
    if (mode == 1) {
        int f0 = lane * 4;
        bf16x4 ob;
#pragma unroll
        for (int k = 0; k < 4; ++k) {
            float v = acc[0][k] + loadf(bias, f0 + k, isf32);
            v = (v > 0.f) ? v : (__expf(v) - 1.f);
            v += bf2f(identb[(size_t)d * F + f0 + k]);
            ob[k] = f2bfs(v);
        }
        *(bf16x4*)(outb + (size_t)d * F + f0) = ob;
    } else {
        float* scratch = &el[wid][0];
#pragma unroll
        for (int j = 0; j < 2; ++j) {
            int f0 = (lane + 64 * j) * 4;
            if (j < nj && f0 < F) {
#pragma unroll
                for (int k = 0; k < 4; ++k) scratch[f0 + k] = acc[j][k];
            }
        }
        wave_lds_fence();
        if (lane < 32) {
            float s = 0.f;
            for (int h = 0; h < H; ++h) s += scratch[h * 32 + lane];
            float v = s * (1.f / (float)H) + loadf(bias, lane, isf32)
                    + bf2f(identb[(size_t)d * 32 + lane]);
            if (isf32) ((float*)out)[(size_t)d * 32 + lane] = v;
            else ((bf16*)out)[(size_t)d * 32 + lane] = __float2bfloat16(v);
        }
    }
}

extern "C" void kernel_launch(void* const* d_in, const int* in_sizes, int n_in,
                              void* d_out, int out_size, void* d_ws, size_t ws_size,
                              hipStream_t stream) {
    const int IN = 256, C = 32;
    const int N = in_sizes[0] / IN;
    const int E = in_sizes[1] / 2;
    const int ET = E + N;

    const void* x    = d_in[0];
    const int*  edge = (const int*)d_in[1];
    const void* W1 = d_in[2];
    const void* a1s = d_in[3];
    const void* a1d = d_in[4];
    const void* b1 = d_in[5];
    const void* W2 = d_in[6];
    const void* a2s = d_in[7];
    const void* a2d = d_in[8];
    const void* b2 = d_in[9];
    const void* W3 = d_in[10];
    const void* a3s = d_in[11];
    const void* a3d = d_in[12];
    const void* b3 = d_in[13];
    const void* P1W = d_in[14];
    const void* P1b = d_in[15];
    const void* P3W = d_in[16];
    const void* P3b = d_in[17];

    char* ws = (char*)d_ws;
    size_t off = 0;
    auto alloc = [&](size_t bytes) -> void* {
        void* p = ws + off;
        off = (off + bytes + 255) & ~(size_t)255;
        return p;
    };
    bf16* fxb   = (bf16*)alloc((size_t)N * 256 * 2);    // bf16 input (f32 world only)
    bf16* fyb   = (bf16*)alloc((size_t)N * 256 * 2);    // bf16 layer outputs
    bf16* fhb   = (bf16*)alloc((size_t)N * 320 * 2);    // h_lin bf16 (per layer)
    bf16* fidb  = (bf16*)alloc((size_t)N * 256 * 2);    // identity1 / identity3 (bf16)
    float* fasrc = (float*)alloc((size_t)N * 10 * 4);
    float* fadst = (float*)alloc((size_t)N * 10 * 4);
    bf16* wc1   = (bf16*)alloc((size_t)512 * 256 * 2);  // [W1; P1W]
    bf16* wb2   = (bf16*)alloc((size_t)256 * 256 * 2);
    bf16* wc3   = (bf16*)alloc((size_t)384 * 256 * 2);  // [W3; P3W; 32 pad rows]
    int*  isrc  = (int*)alloc((size_t)E * 4);
    int*  idst  = (int*)alloc((size_t)E * 4);
    int*  irow  = (int*)alloc((size_t)(N + 1) * 4);
    int*  icur  = (int*)alloc((size_t)N * 4);
    int*  icsr  = (int*)alloc((size_t)ET * 4);
    int*  flags = (int*)alloc(4 * 4);
    (void)ws_size;

    auto cdiv = [](int a, int b) { return (a + b - 1) / b; };

    // zero flags + degree counters
    k_zero<<<cdiv(N, 256), 256, 0, stream>>>(flags, icur, N);

    // dtype detection (tiny prefix probe, spread over ~24 blocks)
    int nprobe_x = (N * 256 < 16384) ? N * 256 : 16384;
    int nprobe_e = (2 * E < 8192) ? 2 * E : 8192;
    int bx = cdiv(nprobe_x, 256) < 16 ? cdiv(nprobe_x, 256) : 16;
    int be = cdiv(nprobe_e, 256) < 8 ? cdiv(nprobe_e, 256) : 8;
    k_detect<<<bx + be, 256, 0, stream>>>(
        (const unsigned short*)x, edge, flags, nprobe_x, nprobe_e, bx);

    // casts + edge normalize + degree count in one launch
    int c_x = N * 256 / 8, c_w = 256 * 256 / 8, c_w3 = 320 * 256 / 8, c_p3 = 32 * 256 / 8;
    int ctot = c_x + 3 * c_w + c_w3 + c_p3;
    int cb = cdiv(ctot, 256);
    k_cast_norm<<<cb + cdiv(E, 256), 256, 0, stream>>>(
        x, fxb, c_x,
        W1, wc1, c_w,
        P1W, wc1 + (size_t)256 * 256, c_w,
        W2, wb2, c_w,
        W3, wc3, c_w3,
        P3W, wc3 + (size_t)320 * 256, c_p3,
        edge, isrc, idst, icur, E, flags, cb);

    k_scan<<<1, 1024, 0, stream>>>(icur, irow, N);
    k_fill<<<cdiv(ET, 256), 256, 0, stream>>>(idst, icur, irow, icsr, E, N);

    int gx = cdiv(N, 64);
    int ga = cdiv(N, 4);

    // ---- Layer 1: H=8; combined [W1;P1W] GEMM + fused alpha (x zero-copy) ----
    {
        int H = 8;
        k_gemm_split<4, 256><<<dim3(gx, 8), 256, 0, stream>>>(
            fxb, x, wc1, P1b, flags, fhb, 256, 256, fidb, 256, 256, N, 512,
            a1s, a1d, fasrc, fadst, H);
        k_fused_agg<<<ga, 256, 0, stream>>>(fhb, fasrc, fadst, isrc, irow, icsr,
                                            b1, fidb, nullptr, fyb, flags, E, N, H, 1);
    }
    // ---- Layer 2: H=8, identity = layer-1 output (bf16, in-place) ----
    {
        int H = 8;
        k_gemm_split<4, 256><<<dim3(gx, 4), 256, 0, stream>>>(
            fyb, nullptr, wb2, nullptr, flags, fhb, 256, 256, nullptr, 0, 0, N, 256,
            a2s, a2d, fasrc, fadst, H);
        k_fused_agg<<<ga, 256, 0, stream>>>(fhb, fasrc, fadst, isrc, irow, icsr,
                                            b2, fyb, nullptr, fyb, flags, E, N, H, 1);
    }
    // ---- Layer 3: H=10, concat=False; combined [W3;P3W;pad] GEMM ----
    {
        int H = 10;
        k_gemm_split<4, 256><<<dim3(gx, 6), 256, 0, stream>>>(
            fyb, nullptr, wc3, P3b, flags, fhb, 320, 320, fidb, 32, 32, N, 384,
            a3s, a3d, fasrc, fadst, H);
        k_fused_agg<<<ga, 256, 0, stream>>>(fhb, fasrc, fadst, isrc, irow, icsr,
                                            b3, fidb, d_out, nullptr, flags, E, N, H, 2);
    }
}